// Round 1
// baseline (387.094 us; speedup 1.0000x reference)
//
#include <hip/hip_runtime.h>

#define NT   49      // tokens per window
#define HD   32      // head dim
#define NH   4
#define DIM  128
#define SCALEQ 0.17677669529663687f  // 32^-0.5

typedef __attribute__((ext_vector_type(8))) short short8;
typedef __attribute__((ext_vector_type(4))) float floatx4;

__device__ __forceinline__ short f2b(float f) {
    union { float f; unsigned u; } v; v.f = f;
    return (short)((v.u + 0x7fffu + ((v.u >> 16) & 1u)) >> 16);  // RNE fp32->bf16
}

// ---------- prologue: bf16 weight conversion + relative-bias gather ----------
__global__ void wmsa_prep(const float* __restrict__ qkvw, const float* __restrict__ projw,
                          const float* __restrict__ btab, const int* __restrict__ ridx,
                          short* __restrict__ wqkv, short* __restrict__ wproj,
                          float* __restrict__ biasg) {
    int i = blockIdx.x * 256 + threadIdx.x;
    if (i < 3 * DIM * DIM) wqkv[i] = f2b(qkvw[i]);          // (384,128)
    if (i < DIM * DIM)     wproj[i] = f2b(projw[i]);        // (128,128)
    if (i < NH * NT * NT) {                                  // biasg[h][i][j]
        int h = i / (NT * NT), ij = i % (NT * NT);
        biasg[i] = btab[ridx[ij] * NH + h];
    }
}

// LDS layout (bytes). Strides padded so every frag read/scatter is <=2-way bank
// aliased (free on CDNA4, m136). Overlaps are phase-disjoint (barriers noted).
//   X  @0      : [64][136] bf16 = 17408   (dead after qkv A-frag loads)
//   P  @0      : [4*49][72] bf16 = 28224  (written after barrier 2)
//   Q  @28224  : [4*49][40] bf16 = 15680
//   K  @43904  : [4*49][40] bf16 = 15680  (dead after S; O overlaps it)
//   O  @43904  : [64][136] bf16           (written after barrier 3)
//   Vt @59584  : [128][72] bf16 = 18432   (token pads 49..71 zeroed)
#define XOFF 0
#define XSTR 136
#define POFF 0
#define PSTR 72
#define QOFF 28224
#define QSTR 40
#define KOFF 43904
#define OOFF 43904
#define OSTR 136
#define VOFF 59584
#define VSTR 72
#define LDSB 78016   // <= 81920 -> 2 blocks/CU

__global__ __launch_bounds__(256, 2) void wmsa_main(
    const float* __restrict__ x, const float* __restrict__ mask,
    const float* __restrict__ qkvb, const float* __restrict__ projb,
    const short* __restrict__ wqkv, const short* __restrict__ wproj,
    const float* __restrict__ biasg, float* __restrict__ out)
{
    __shared__ __align__(16) char pool[LDSB];
    short* lds = (short*)pool;

    const int b    = blockIdx.x;
    const int wdw  = b & 63;           // window index for attn_mask
    const int tid  = threadIdx.x;
    const int wave = tid >> 6;
    const int lane = tid & 63;
    const int qq   = lane >> 4;        // quad 0..3
    const int cc   = lane & 15;

    // ---------------- Phase 0: stage x -> bf16 LDS, zero Vt token pads ----------------
    {
        const float* xb = x + (size_t)b * NT * DIM;
        for (int i = tid; i < NT * (DIM / 4); i += 256) {
            int t = i >> 5, c4 = (i & 31) << 2;
            float4 v = *(const float4*)(xb + t * DIM + c4);
            unsigned long long pk =
                  (unsigned long long)(unsigned short)f2b(v.x)
                | ((unsigned long long)(unsigned short)f2b(v.y) << 16)
                | ((unsigned long long)(unsigned short)f2b(v.z) << 32)
                | ((unsigned long long)(unsigned short)f2b(v.w) << 48);
            *(unsigned long long*)(lds + t * XSTR + c4) = pk;
        }
        short* vt = (short*)(pool + VOFF);
        for (int i = tid; i < 128 * (64 - NT); i += 256) {   // zero tokens 49..63 (read extent)
            int d = i / (64 - NT), t = NT + i % (64 - NT);
            vt[d * VSTR + t] = 0;
        }
    }
    __syncthreads();   // barrier 1

    // ---------------- Phase 1: QKV GEMM (M=64 pad, N=384, K=128) ----------------
    {
        short8 af[4][4];                                 // A frags held in regs (X dead after)
        #pragma unroll
        for (int it = 0; it < 4; ++it)
            #pragma unroll
            for (int ks = 0; ks < 4; ++ks)
                af[it][ks] = *(const short8*)(lds + (it * 16 + cc) * XSTR + ks * 32 + qq * 8);

        #pragma unroll
        for (int jt6 = 0; jt6 < 6; ++jt6) {
            int jt  = wave * 6 + jt6;
            int col = jt * 16 + cc;                      // 0..383
            short8 bf[4];
            #pragma unroll
            for (int ks = 0; ks < 4; ++ks)
                bf[ks] = *(const short8*)(wqkv + col * DIM + ks * 32 + qq * 8);
            float bias = qkvb[col];
            int sec = col >> 7, hh = (col >> 5) & 3, dd = col & 31;   // wave-uniform per jt
            #pragma unroll
            for (int it = 0; it < 4; ++it) {
                floatx4 acc = {0.f, 0.f, 0.f, 0.f};
                #pragma unroll
                for (int ks = 0; ks < 4; ++ks)
                    acc = __builtin_amdgcn_mfma_f32_16x16x32_bf16(af[it][ks], bf[ks], acc, 0, 0, 0);
                #pragma unroll
                for (int r = 0; r < 4; ++r) {
                    int row = it * 16 + qq * 4 + r;
                    if (row < NT) {
                        float v = acc[r] + bias;
                        if (sec == 0)
                            *(short*)(pool + QOFF + (((hh * NT + row) * QSTR) + dd) * 2) = f2b(v * SCALEQ);
                        else if (sec == 1)
                            *(short*)(pool + KOFF + (((hh * NT + row) * QSTR) + dd) * 2) = f2b(v);
                        else
                            *(short*)(pool + VOFF + (((hh * HD + dd) * VSTR) + row) * 2) = f2b(v);
                    }
                }
            }
        }
    }
    __syncthreads();   // barrier 2: Q/K/Vt visible to all waves

    // ---------------- Phase 2: attention, one head per wave ----------------
    const int h = wave;
    floatx4 o[4][2];
    {
        short8 qf[4], kf[4];
        #pragma unroll
        for (int t = 0; t < 4; ++t) {
            qf[t] = *(const short8*)(pool + QOFF + (((h * NT + t * 16 + cc) * QSTR) + qq * 8) * 2);
            kf[t] = *(const short8*)(pool + KOFF + (((h * NT + t * 16 + cc) * QSTR) + qq * 8) * 2);
        }
        floatx4 s[4][4];
        #pragma unroll
        for (int it = 0; it < 4; ++it)
            #pragma unroll
            for (int jt = 0; jt < 4; ++jt) {
                floatx4 z = {0.f, 0.f, 0.f, 0.f};
                s[it][jt] = __builtin_amdgcn_mfma_f32_16x16x32_bf16(qf[it], kf[jt], z, 0, 0, 0);
            }

        // softmax over key dim; rows live in fixed (qq) quads, butterfly over cc
        const float* bh = biasg + h * NT * NT;
        const float* mw = mask + wdw * NT * NT;
        #pragma unroll
        for (int it = 0; it < 4; ++it) {
            float pv[4][4];   // [r][jt]
            float inv[4];
            #pragma unroll
            for (int r = 0; r < 4; ++r) {
                int row = it * 16 + qq * 4 + r;
                bool rv = row < NT;
                float vv[4];
                float mx = -1e30f;
                #pragma unroll
                for (int jt = 0; jt < 4; ++jt) {
                    int colj = jt * 16 + cc;
                    float v = -1e30f;
                    if (rv && colj < NT)
                        v = s[it][jt][r] + bh[row * NT + colj] + mw[row * NT + colj];
                    vv[jt] = v;
                    mx = fmaxf(mx, v);
                }
                #pragma unroll
                for (int d = 1; d < 16; d <<= 1) mx = fmaxf(mx, __shfl_xor(mx, d));
                float sum = 0.f;
                #pragma unroll
                for (int jt = 0; jt < 4; ++jt) {
                    float p = __expf(vv[jt] - mx);
                    pv[r][jt] = p;
                    sum += p;
                }
                #pragma unroll
                for (int d = 1; d < 16; d <<= 1) sum += __shfl_xor(sum, d);
                inv[r] = 1.0f / sum;
            }
            #pragma unroll
            for (int r = 0; r < 4; ++r) {
                int row = it * 16 + qq * 4 + r;
                if (row < NT) {
                    #pragma unroll
                    for (int jt = 0; jt < 4; ++jt)
                        *(short*)(pool + POFF + (((h * NT + row) * PSTR) + jt * 16 + cc) * 2)
                            = f2b(pv[r][jt] * inv[r]);
                }
            }
        }
    }
    __syncthreads();   // barrier 3: P visible; K reads complete (O overlaps K)

    // ---------------- Phase 3: O = P @ V ----------------
    {
        #pragma unroll
        for (int it = 0; it < 4; ++it)
            #pragma unroll
            for (int jv = 0; jv < 2; ++jv)
                o[it][jv] = (floatx4){0.f, 0.f, 0.f, 0.f};
        #pragma unroll
        for (int ks = 0; ks < 2; ++ks) {
            short8 pf[4], vf[2];
            #pragma unroll
            for (int it = 0; it < 4; ++it)
                pf[it] = *(const short8*)(pool + POFF + (((h * NT + it * 16 + cc) * PSTR) + ks * 32 + qq * 8) * 2);
            #pragma unroll
            for (int jv = 0; jv < 2; ++jv)
                vf[jv] = *(const short8*)(pool + VOFF + (((h * HD + jv * 16 + cc) * VSTR) + ks * 32 + qq * 8) * 2);
            #pragma unroll
            for (int it = 0; it < 4; ++it)
                #pragma unroll
                for (int jv = 0; jv < 2; ++jv)
                    o[it][jv] = __builtin_amdgcn_mfma_f32_16x16x32_bf16(pf[it], vf[jv], o[it][jv], 0, 0, 0);
        }
        // scatter O into proj A-operand layout
        #pragma unroll
        for (int it = 0; it < 4; ++it)
            #pragma unroll
            for (int jv = 0; jv < 2; ++jv)
                #pragma unroll
                for (int r = 0; r < 4; ++r) {
                    int row = it * 16 + qq * 4 + r;
                    if (row < NT)
                        *(short*)(pool + OOFF + ((row * OSTR) + h * HD + jv * 16 + cc) * 2) = f2b(o[it][jv][r]);
                }
    }
    __syncthreads();   // barrier 4: O visible

    // ---------------- Phase 4: proj GEMM (M=64 pad, N=128, K=128) ----------------
    {
        short8 af[4];
        #pragma unroll
        for (int ks = 0; ks < 4; ++ks)
            af[ks] = *(const short8*)(pool + OOFF + (((wave * 16 + cc) * OSTR) + ks * 32 + qq * 8) * 2);
        float* outb = out + (size_t)b * NT * DIM;
        #pragma unroll
        for (int jt = 0; jt < 8; ++jt) {
            int col = jt * 16 + cc;
            short8 bf[4];
            #pragma unroll
            for (int ks = 0; ks < 4; ++ks)
                bf[ks] = *(const short8*)(wproj + col * DIM + ks * 32 + qq * 8);
            floatx4 acc = {0.f, 0.f, 0.f, 0.f};
            #pragma unroll
            for (int ks = 0; ks < 4; ++ks)
                acc = __builtin_amdgcn_mfma_f32_16x16x32_bf16(af[ks], bf[ks], acc, 0, 0, 0);
            float pb = projb[col];
            #pragma unroll
            for (int r = 0; r < 4; ++r) {
                int row = wave * 16 + qq * 4 + r;
                if (row < NT) outb[row * DIM + col] = acc[r] + pb;
            }
        }
    }
}

extern "C" void kernel_launch(void* const* d_in, const int* in_sizes, int n_in,
                              void* d_out, int out_size, void* d_ws, size_t ws_size,
                              hipStream_t stream) {
    const float* x     = (const float*)d_in[0];   // (4096,49,128)
    const float* mask  = (const float*)d_in[1];   // (64,49,49)
    const float* qkvw  = (const float*)d_in[2];   // (384,128)
    const float* qkvb  = (const float*)d_in[3];   // (384)
    const float* projw = (const float*)d_in[4];   // (128,128)
    const float* projb = (const float*)d_in[5];   // (128)
    const float* btab  = (const float*)d_in[6];   // (169,4)
    const int*   ridx  = (const int*)d_in[7];     // (49,49)
    float* outp = (float*)d_out;

    short* wqkv  = (short*)d_ws;                          // 98304 B
    short* wproj = (short*)((char*)d_ws + 98304);         // 32768 B
    float* biasg = (float*)((char*)d_ws + 131072);        // 38416 B

    wmsa_prep<<<192, 256, 0, stream>>>(qkvw, projw, btab, ridx, wqkv, wproj, biasg);
    wmsa_main<<<4096, 256, 0, stream>>>(x, mask, qkvb, projb, wqkv, wproj, biasg, outp);
}

// Round 4
// 325.898 us; speedup vs baseline: 1.1878x; 1.1878x over previous
//
#include <hip/hip_runtime.h>

#define NT   49      // tokens per window
#define HD   32      // head dim
#define NH   4
#define DIM  128
#define SCALEQ 0.17677669529663687f  // 32^-0.5

typedef __attribute__((ext_vector_type(8))) short short8;
typedef __attribute__((ext_vector_type(4))) short short4v;
typedef __attribute__((ext_vector_type(4))) float floatx4;
// may_alias versions: all LDS/global type-punned accesses go through these so
// TBAA cannot reorder stores/loads across the barrier-free phase chain.
typedef short8 short8a __attribute__((may_alias));
typedef short4v short4a __attribute__((may_alias));
typedef unsigned long long ulla __attribute__((may_alias));
typedef unsigned long long ull;

__device__ __forceinline__ short f2b(float f) {
    union { float f; unsigned u; } v; v.f = f;
    return (short)((v.u + 0x7fffu + ((v.u >> 16) & 1u)) >> 16);  // RNE fp32->bf16
}
__device__ __forceinline__ float b2f(short s) {
    union { unsigned u; float f; } v; v.u = ((unsigned)(unsigned short)s) << 16;
    return v.f;
}

// ---------- prologue: bf16 weights (Q pre-scaled) + bias table in frag layout ----------
// b4 packed as [h][it][jt][qq][cc][r] bf16 so one 8B load yields a lane's 4 C-init
// values for S-tile (it,jt). col>=49 -> -1e30 (key-pad mask folded into C-init),
// row>=49 -> 0 (garbage rows, discarded later).
__global__ void wmsa_prep(const float* __restrict__ qkvw, const float* __restrict__ projw,
                          const float* __restrict__ btab, const int* __restrict__ ridx,
                          short* __restrict__ wqkv, short* __restrict__ wproj,
                          short* __restrict__ b4) {
    int i = blockIdx.x * 256 + threadIdx.x;
    if (i < 3 * DIM * DIM) {
        float s = (i < DIM * DIM) ? SCALEQ : 1.0f;   // rows 0..127 = Q section
        wqkv[i] = f2b(qkvw[i] * s);
    }
    if (i < DIM * DIM) wproj[i] = f2b(projw[i]);
    if (i < NH * 64 * 64) {
        int h = i >> 12, row = (i >> 6) & 63, col = i & 63;
        float v;
        if (col >= NT)      v = -1e30f;
        else if (row >= NT) v = 0.f;
        else                v = btab[ridx[row * NT + col] * NH + h];
        int it = row >> 4, qq = (row >> 2) & 3, r = row & 3;
        int jt = col >> 4, cc = col & 15;
        b4[(((h * 4 + it) * 4 + jt) * 4 + qq) * 64 + cc * 4 + r] = f2b(v);
    }
}

// LDS pool (51200 B -> 3 blocks/CU). Per-wave private region R=12800 B at w*12800:
//   Q @+0    [64 rows][32] bf16, XOR-swizzled 8-short groups   = 4096
//   K @+4096 same                                              = 4096
//   V @+8192 [32 dims][72 tokens] bf16                         = 4608
//   P @+0    [64 rows][64] bf16 swizzled (overlaps dead Q+K)   = 8192
// Block-shared, phase-disjoint overlays:
//   X @0 [64][136] bf16 = 17408 (dead after barrier 2)
//   O @0 [64][136] bf16 = 17408 (written after barrier 3; stride MUST be >=128
//                                — the R2 bug was stride 72 colliding rows)
#define RWAVE 12800
#define OSTR  136
#define LDSB  51200

__global__ __launch_bounds__(256, 3) void wmsa_main(
    const float* __restrict__ x, const float* __restrict__ mask,
    const float* __restrict__ qkvb, const float* __restrict__ projb,
    const short* __restrict__ wqkv, const short* __restrict__ wproj,
    const short* __restrict__ b4, float* __restrict__ out)
{
    __shared__ __align__(16) char pool[LDSB];
    short* lds = (short*)pool;

    const int b    = blockIdx.x;
    const int wdw  = b & 63;
    const int tid  = threadIdx.x;
    const int wave = tid >> 6;
    const int lane = tid & 63;
    const int qq   = lane >> 4;        // quad 0..3
    const int cc   = lane & 15;
    const int ccl  = cc & 7, cch = cc >> 3, cm3 = cc & 3;

    // ---------------- Phase 0: stage x -> bf16 LDS (stride 136), zero pad rows ----------------
    {
        const float* xb = x + (size_t)b * NT * DIM;
        for (int i = tid; i < NT * 32; i += 256) {
            int t = i >> 5, c4 = (i & 31) << 2;
            float4 v = *(const float4*)(xb + t * DIM + c4);
            ull pk =  (ull)(unsigned short)f2b(v.x)
                    | ((ull)(unsigned short)f2b(v.y) << 16)
                    | ((ull)(unsigned short)f2b(v.z) << 32)
                    | ((ull)(unsigned short)f2b(v.w) << 48);
            *(ulla*)(lds + t * 136 + c4) = pk;
        }
        for (int i = tid; i < (64 - NT) * 32; i += 256) {   // zero rows 49..63
            int t = NT + (i >> 5), c4 = (i & 31) << 2;
            *(ulla*)(lds + t * 136 + c4) = 0ull;
        }
    }
    __syncthreads();   // B1: X staged

    // A-frags of X for all 4 row tiles (held in regs through phase 1)
    short8 af[4][4];
    #pragma unroll
    for (int it = 0; it < 4; ++it)
        #pragma unroll
        for (int ks = 0; ks < 4; ++ks)
            af[it][ks] = *(const short8a*)(lds + (it * 16 + cc) * 136 + ks * 32 + qq * 8);
    __syncthreads();   // B2: X reads done; per-wave regions may be written

    short* qw = (short*)(pool + wave * RWAVE);
    short* kw = qw + 2048;     // +4096 B
    short* vw = qw + 4096;     // +8192 B
    short* pw = qw;            // P overlays Q+K after S

    // ---------------- Phase 1: wave h computes Q/K/V columns of head h only ----------------
    #pragma unroll
    for (int jt6 = 0; jt6 < 6; ++jt6) {
        const int sec = jt6 >> 1, hlf = jt6 & 1;             // compile-time
        const int col = sec * DIM + wave * 32 + hlf * 16 + cc;
        short8 bf[4];
        #pragma unroll
        for (int ks = 0; ks < 4; ++ks)
            bf[ks] = *(const short8a*)(wqkv + col * DIM + ks * 32 + qq * 8);
        float bias = qkvb[col];
        if (sec == 0) bias *= SCALEQ;
        const floatx4 cinit = {bias, bias, bias, bias};
        #pragma unroll
        for (int it = 0; it < 4; ++it) {
            floatx4 acc = cinit;
            #pragma unroll
            for (int ks = 0; ks < 4; ++ks)
                acc = __builtin_amdgcn_mfma_f32_16x16x32_bf16(af[it][ks], bf[ks], acc, 0, 0, 0);
            if (sec == 2) {                                   // V: transposed, pack 4 tokens
                int dd = hlf * 16 + cc;
                int t0 = it * 16 + qq * 4;
                ull pk =  (ull)(unsigned short)f2b(acc[0])
                        | ((ull)(unsigned short)f2b(acc[1]) << 16)
                        | ((ull)(unsigned short)f2b(acc[2]) << 32)
                        | ((ull)(unsigned short)f2b(acc[3]) << 48);
                *(ulla*)(vw + dd * 72 + t0) = pk;
            } else {                                          // Q/K: [t][d] swizzled
                short* dst = (sec == 0) ? qw : kw;
                int gb = hlf * 2 + cch;                       // d>>3
                #pragma unroll
                for (int r = 0; r < 4; ++r) {                 // t&3 == r
                    int t = it * 16 + qq * 4 + r;
                    dst[t * 32 + ((gb ^ r) << 3) + ccl] = f2b(acc[r]);
                }
            }
        }
    }
    __asm__ volatile("" ::: "memory");   // intra-wave phase fence: QKV stores -> S loads

    // ---------------- Phase 2: S = Q K^T (+bias C-init), softmax, P ----------------
    {
        short8 qf[4], kf[4];
        #pragma unroll
        for (int t = 0; t < 4; ++t) {
            qf[t] = *(const short8a*)(qw + (t * 16 + cc) * 32 + ((qq ^ cm3) << 3));
            kf[t] = *(const short8a*)(kw + (t * 16 + cc) * 32 + ((qq ^ cm3) << 3));
        }
        const short* b4w = b4 + wave * 4096;
        const float* mw  = mask + (size_t)wdw * NT * NT;
        #pragma unroll
        for (int it = 0; it < 4; ++it) {
            floatx4 s[4];
            #pragma unroll
            for (int jt = 0; jt < 4; ++jt) {
                short4v cb = *(const short4a*)(b4w + ((it * 4 + jt) * 4 + qq) * 64 + cc * 4);
                floatx4 ci = {b2f(cb.x), b2f(cb.y), b2f(cb.z), b2f(cb.w)};
                s[jt] = __builtin_amdgcn_mfma_f32_16x16x32_bf16(qf[it], kf[jt], ci, 0, 0, 0);
            }
            float e[4][4], inv[4];
            #pragma unroll
            for (int r = 0; r < 4; ++r) {
                int row = it * 16 + qq * 4 + r;
                float sm = 0.f;
                #pragma unroll
                for (int jt = 0; jt < 4; ++jt) {
                    int colj = jt * 16 + cc;
                    float mv = (row < NT && colj < NT) ? mw[row * NT + colj] : 0.f;
                    float ee = __expf(s[jt][r] + mv);   // no max-sub: logits O(1); pads -> exp(-1e30)=0
                    e[r][jt] = ee;
                    sm += ee;
                }
                #pragma unroll
                for (int d = 1; d < 16; d <<= 1) sm += __shfl_xor(sm, d);
                inv[r] = 1.0f / sm;
            }
            #pragma unroll
            for (int r = 0; r < 4; ++r) {
                int t = it * 16 + qq * 4 + r;
                #pragma unroll
                for (int jt = 0; jt < 4; ++jt) {
                    int g = (jt * 2 + cch) ^ r;           // (col>>3) ^ (t&3)
                    pw[t * 64 + (g << 3) + ccl] = f2b(e[r][jt] * inv[r]);
                }
            }
        }
    }
    __asm__ volatile("" ::: "memory");   // intra-wave phase fence: P stores -> PV loads

    // ---------------- Phase 3: O = P @ V (wave-private) ----------------
    floatx4 o[4][2];
    #pragma unroll
    for (int it = 0; it < 4; ++it)
        #pragma unroll
        for (int jv = 0; jv < 2; ++jv)
            o[it][jv] = (floatx4){0.f, 0.f, 0.f, 0.f};
    #pragma unroll
    for (int ks = 0; ks < 2; ++ks) {
        short8 pf[4], vf[2];
        #pragma unroll
        for (int it = 0; it < 4; ++it)
            pf[it] = *(const short8a*)(pw + (it * 16 + cc) * 64 + (((ks * 4 + qq) ^ cm3) << 3));
        #pragma unroll
        for (int jv = 0; jv < 2; ++jv)
            vf[jv] = *(const short8a*)(vw + (jv * 16 + cc) * 72 + ks * 32 + qq * 8);
        #pragma unroll
        for (int it = 0; it < 4; ++it)
            #pragma unroll
            for (int jv = 0; jv < 2; ++jv)
                o[it][jv] = __builtin_amdgcn_mfma_f32_16x16x32_bf16(pf[it], vf[jv], o[it][jv], 0, 0, 0);
    }
    __syncthreads();   // B3: all PV reads done -> O may overlay waves 0-1 regions

    short* ow = (short*)pool;   // O [64 tokens][OSTR=136], features 0..127
    #pragma unroll
    for (int it = 0; it < 4; ++it)
        #pragma unroll
        for (int jv = 0; jv < 2; ++jv)
            #pragma unroll
            for (int r = 0; r < 4; ++r) {
                int t = it * 16 + qq * 4 + r;
                ow[t * OSTR + wave * 32 + jv * 16 + cc] = f2b(o[it][jv][r]);
            }
    __syncthreads();   // B4: O visible

    // ---------------- Phase 4: proj GEMM ----------------
    {
        short8 a2[4];
        #pragma unroll
        for (int ks = 0; ks < 4; ++ks)
            a2[ks] = *(const short8a*)(ow + (wave * 16 + cc) * OSTR + ks * 32 + qq * 8);
        float* outb = out + (size_t)b * NT * DIM;
        #pragma unroll
        for (int jt = 0; jt < 8; ++jt) {
            int col = jt * 16 + cc;
            short8 bfp[4];
            #pragma unroll
            for (int ks = 0; ks < 4; ++ks)
                bfp[ks] = *(const short8a*)(wproj + col * DIM + ks * 32 + qq * 8);
            float pb = projb[col];
            floatx4 acc = {pb, pb, pb, pb};
            #pragma unroll
            for (int ks = 0; ks < 4; ++ks)
                acc = __builtin_amdgcn_mfma_f32_16x16x32_bf16(a2[ks], bfp[ks], acc, 0, 0, 0);
            #pragma unroll
            for (int r = 0; r < 4; ++r) {
                int row = wave * 16 + qq * 4 + r;
                if (row < NT) outb[row * DIM + col] = acc[r];
            }
        }
    }
}

extern "C" void kernel_launch(void* const* d_in, const int* in_sizes, int n_in,
                              void* d_out, int out_size, void* d_ws, size_t ws_size,
                              hipStream_t stream) {
    const float* x     = (const float*)d_in[0];   // (4096,49,128)
    const float* mask  = (const float*)d_in[1];   // (64,49,49)
    const float* qkvw  = (const float*)d_in[2];   // (384,128)
    const float* qkvb  = (const float*)d_in[3];   // (384)
    const float* projw = (const float*)d_in[4];   // (128,128)
    const float* projb = (const float*)d_in[5];   // (128)
    const float* btab  = (const float*)d_in[6];   // (169,4)
    const int*   ridx  = (const int*)d_in[7];     // (49,49)
    float* outp = (float*)d_out;

    short* wqkv  = (short*)d_ws;                      //  98304 B
    short* wproj = (short*)((char*)d_ws + 98304);     //  32768 B
    short* b4    = (short*)((char*)d_ws + 131072);    //  32768 B  (total 163840)

    wmsa_prep<<<192, 256, 0, stream>>>(qkvw, projw, btab, ridx, wqkv, wproj, b4);
    wmsa_main<<<4096, 256, 0, stream>>>(x, mask, qkvb, projb, wqkv, wproj, b4, outp);
}

// Round 5
// 301.615 us; speedup vs baseline: 1.2834x; 1.0805x over previous
//
#include <hip/hip_runtime.h>

#define NT   49      // tokens per window
#define HD   32      // head dim
#define NH   4
#define DIM  128
#define SCALEQ 0.17677669529663687f  // 32^-0.5

typedef __attribute__((ext_vector_type(8))) short short8;
typedef __attribute__((ext_vector_type(4))) short short4v;
typedef __attribute__((ext_vector_type(4))) float floatx4;
// may_alias versions: all LDS/global type-punned accesses go through these so
// TBAA cannot reorder stores/loads across the barrier-free phase chain.
typedef short8 short8a __attribute__((may_alias));
typedef short4v short4a __attribute__((may_alias));
typedef unsigned long long ulla __attribute__((may_alias));
typedef unsigned long long ull;

__device__ __forceinline__ short f2b(float f) {
    union { float f; unsigned u; } v; v.f = f;
    return (short)((v.u + 0x7fffu + ((v.u >> 16) & 1u)) >> 16);  // RNE fp32->bf16
}
__device__ __forceinline__ float b2f(short s) {
    union { unsigned u; float f; } v; v.u = ((unsigned)(unsigned short)s) << 16;
    return v.f;
}

// ---------- prologue ----------
// wqkv: bf16, Q section pre-scaled by hd^-0.5.
// cmb[wdw][h][(it*4+jt)*256 + qq*64 + cc*4 + r] bf16 = bias[h] + mask[wdw] with
// pads folded in: col>=49 -> -1e30 (masks key pads via C-init), row>=49 -> 0.
// One 8B load per S-tile replaces 4 bias loads + 4 scalar mask loads (R4's
// dominant stall: 64 serial scalar loads/lane inside the softmax).
__global__ void wmsa_prep(const float* __restrict__ qkvw, const float* __restrict__ projw,
                          const float* __restrict__ btab, const int* __restrict__ ridx,
                          const float* __restrict__ mask,
                          short* __restrict__ wqkv, short* __restrict__ wproj,
                          short* __restrict__ cmb) {
    int i = blockIdx.x * 256 + threadIdx.x;
    if (i < 3 * DIM * DIM) {
        float s = (i < DIM * DIM) ? SCALEQ : 1.0f;   // rows 0..127 = Q section
        wqkv[i] = f2b(qkvw[i] * s);
    }
    if (i < DIM * DIM) wproj[i] = f2b(projw[i]);
    if (i < 64 * NH * 4096) {
        int wdw = i >> 14, rem = i & 16383;
        int h = rem >> 12, e = rem & 4095;
        int tile = e >> 8, r2 = e & 255;
        int it = tile >> 2, jt = tile & 3;
        int qq = r2 >> 6, cr = r2 & 63, cc = cr >> 2, r = cr & 3;
        int row = it * 16 + qq * 4 + r, col = jt * 16 + cc;
        float v;
        if (col >= NT)      v = -1e30f;
        else if (row >= NT) v = 0.f;
        else                v = btab[ridx[row * NT + col] * NH + h]
                              + mask[wdw * NT * NT + row * NT + col];
        cmb[i] = f2b(v);
    }
}

// LDS pool (51200 B -> 3 blocks/CU). Per-wave private region R=12800 B at w*12800:
//   Q @+0    [64 rows][32] bf16, XOR-swizzled 8-short groups   = 4096
//   K @+4096 same                                              = 4096
//   V @+8192 [32 dims][72 tokens] bf16                         = 4608
//   P @+0    [64 rows][64] bf16 swizzled (overlaps dead Q+K)   = 8192
// Block-shared, phase-disjoint overlays:
//   X @0 [64][136] bf16 = 17408 (dead after barrier 2)
//   O @0 [64][136] bf16 = 17408 (after barrier 3; stride >=128 — R2 bug was 72)
#define RWAVE 12800
#define OSTR  136
#define LDSB  51200

__global__ __launch_bounds__(256, 3) void wmsa_main(
    const float* __restrict__ x,
    const float* __restrict__ qkvb, const float* __restrict__ projb,
    const short* __restrict__ wqkv, const short* __restrict__ wproj,
    const short* __restrict__ cmb, float* __restrict__ out)
{
    __shared__ __align__(16) char pool[LDSB];
    short* lds = (short*)pool;

    const int b    = blockIdx.x;
    const int wdw  = b & 63;
    const int tid  = threadIdx.x;
    const int wave = tid >> 6;
    const int lane = tid & 63;
    const int qq   = lane >> 4;        // quad 0..3
    const int cc   = lane & 15;
    const int ccl  = cc & 7, cch = cc >> 3, cm3 = cc & 3;

    // ---- prefetch: jt6=0 B-frags + all 6 qkv biases (complete during staging) ----
    const int colbase = wave * 32 + cc;
    short8 bfc[4], bfn[4];
    #pragma unroll
    for (int ks = 0; ks < 4; ++ks)
        bfc[ks] = *(const short8a*)(wqkv + colbase * DIM + ks * 32 + qq * 8);
    float biasv[6];
    #pragma unroll
    for (int j = 0; j < 6; ++j)
        biasv[j] = qkvb[(j >> 1) * DIM + colbase + (j & 1) * 16];

    // ---------------- Phase 0: stage x -> bf16 LDS (stride 136), zero pad rows ----------------
    {
        const float* xb = x + (size_t)b * NT * DIM;
        for (int i = tid; i < NT * 32; i += 256) {
            int t = i >> 5, c4 = (i & 31) << 2;
            float4 v = *(const float4*)(xb + t * DIM + c4);
            ull pk =  (ull)(unsigned short)f2b(v.x)
                    | ((ull)(unsigned short)f2b(v.y) << 16)
                    | ((ull)(unsigned short)f2b(v.z) << 32)
                    | ((ull)(unsigned short)f2b(v.w) << 48);
            *(ulla*)(lds + t * 136 + c4) = pk;
        }
        for (int i = tid; i < (64 - NT) * 32; i += 256) {   // zero rows 49..63
            int t = NT + (i >> 5), c4 = (i & 31) << 2;
            *(ulla*)(lds + t * 136 + c4) = 0ull;
        }
    }
    __syncthreads();   // B1: X staged

    // A-frags of X for all 4 row tiles (held in regs through phase 1)
    short8 af[4][4];
    #pragma unroll
    for (int it = 0; it < 4; ++it)
        #pragma unroll
        for (int ks = 0; ks < 4; ++ks)
            af[it][ks] = *(const short8a*)(lds + (it * 16 + cc) * 136 + ks * 32 + qq * 8);
    __syncthreads();   // B2: X reads done; per-wave regions may be written

    short* qw = (short*)(pool + wave * RWAVE);
    short* kw = qw + 2048;     // +4096 B
    short* vw = qw + 4096;     // +8192 B
    short* pw = qw;            // P overlays Q+K after S

    // ---------------- Phase 1: wave h computes Q/K/V of head h (pipelined B-frags) ----------------
    #pragma unroll
    for (int jt6 = 0; jt6 < 6; ++jt6) {
        const int sec = jt6 >> 1, hlf = jt6 & 1;             // compile-time
        if (jt6 < 5) {                                        // prefetch next iteration's frags
            const int cn = ((jt6 + 1) >> 1) * DIM + colbase + ((jt6 + 1) & 1) * 16;
            #pragma unroll
            for (int ks = 0; ks < 4; ++ks)
                bfn[ks] = *(const short8a*)(wqkv + cn * DIM + ks * 32 + qq * 8);
        }
        float bias = biasv[jt6];
        if (sec == 0) bias *= SCALEQ;
        const floatx4 cinit = {bias, bias, bias, bias};
        #pragma unroll
        for (int it = 0; it < 4; ++it) {
            floatx4 acc = cinit;
            #pragma unroll
            for (int ks = 0; ks < 4; ++ks)
                acc = __builtin_amdgcn_mfma_f32_16x16x32_bf16(af[it][ks], bfc[ks], acc, 0, 0, 0);
            if (sec == 2) {                                   // V: transposed, pack 4 tokens
                int dd = hlf * 16 + cc;
                int t0 = it * 16 + qq * 4;
                ull pk =  (ull)(unsigned short)f2b(acc[0])
                        | ((ull)(unsigned short)f2b(acc[1]) << 16)
                        | ((ull)(unsigned short)f2b(acc[2]) << 32)
                        | ((ull)(unsigned short)f2b(acc[3]) << 48);
                *(ulla*)(vw + dd * 72 + t0) = pk;
            } else {                                          // Q/K: [t][d] swizzled
                short* dst = (sec == 0) ? qw : kw;
                int gb = hlf * 2 + cch;                       // d>>3
                #pragma unroll
                for (int r = 0; r < 4; ++r) {                 // t&3 == r
                    int t = it * 16 + qq * 4 + r;
                    dst[t * 32 + ((gb ^ r) << 3) + ccl] = f2b(acc[r]);
                }
            }
        }
        #pragma unroll
        for (int ks = 0; ks < 4; ++ks) bfc[ks] = bfn[ks];
    }

    // prefetch all 16 S-tile C-inits (bias+mask combined, bf16 frag layout)
    short4v cm[16];
    {
        const short* cw = cmb + (((size_t)wdw * NH + wave) << 12);
        #pragma unroll
        for (int t16 = 0; t16 < 16; ++t16)
            cm[t16] = *(const short4a*)(cw + t16 * 256 + qq * 64 + cc * 4);
    }
    __asm__ volatile("" ::: "memory");   // intra-wave phase fence: QKV stores -> S loads

    // ---------------- Phase 2: S = Q K^T (+combined C-init), softmax, P ----------------
    {
        short8 qf[4], kf[4];
        #pragma unroll
        for (int t = 0; t < 4; ++t) {
            qf[t] = *(const short8a*)(qw + (t * 16 + cc) * 32 + ((qq ^ cm3) << 3));
            kf[t] = *(const short8a*)(kw + (t * 16 + cc) * 32 + ((qq ^ cm3) << 3));
        }
        #pragma unroll
        for (int it = 0; it < 4; ++it) {
            floatx4 s[4];
            #pragma unroll
            for (int jt = 0; jt < 4; ++jt) {
                short4v cb = cm[it * 4 + jt];
                floatx4 ci = {b2f(cb.x), b2f(cb.y), b2f(cb.z), b2f(cb.w)};
                s[jt] = __builtin_amdgcn_mfma_f32_16x16x32_bf16(qf[it], kf[jt], ci, 0, 0, 0);
            }
            float e[4][4], inv[4];
            #pragma unroll
            for (int r = 0; r < 4; ++r) {
                float sm = 0.f;
                #pragma unroll
                for (int jt = 0; jt < 4; ++jt) {
                    float ee = __expf(s[jt][r]);   // pads -> exp(-1e30)=0; logits O(1): no max-sub
                    e[r][jt] = ee;
                    sm += ee;
                }
                #pragma unroll
                for (int d = 1; d < 16; d <<= 1) sm += __shfl_xor(sm, d);
                inv[r] = 1.0f / sm;
            }
            #pragma unroll
            for (int r = 0; r < 4; ++r) {
                int t = it * 16 + qq * 4 + r;
                #pragma unroll
                for (int jt = 0; jt < 4; ++jt) {
                    int g = (jt * 2 + cch) ^ r;           // (col>>3) ^ (t&3)
                    pw[t * 64 + (g << 3) + ccl] = f2b(e[r][jt] * inv[r]);
                }
            }
        }
    }
    __asm__ volatile("" ::: "memory");   // intra-wave phase fence: P stores -> PV loads

    // ---------------- Phase 3: O = P @ V (wave-private) ----------------
    floatx4 o[4][2];
    #pragma unroll
    for (int it = 0; it < 4; ++it)
        #pragma unroll
        for (int jv = 0; jv < 2; ++jv)
            o[it][jv] = (floatx4){0.f, 0.f, 0.f, 0.f};
    #pragma unroll
    for (int ks = 0; ks < 2; ++ks) {
        short8 pf[4], vf[2];
        #pragma unroll
        for (int it = 0; it < 4; ++it)
            pf[it] = *(const short8a*)(pw + (it * 16 + cc) * 64 + (((ks * 4 + qq) ^ cm3) << 3));
        #pragma unroll
        for (int jv = 0; jv < 2; ++jv)
            vf[jv] = *(const short8a*)(vw + (jv * 16 + cc) * 72 + ks * 32 + qq * 8);
        #pragma unroll
        for (int it = 0; it < 4; ++it)
            #pragma unroll
            for (int jv = 0; jv < 2; ++jv)
                o[it][jv] = __builtin_amdgcn_mfma_f32_16x16x32_bf16(pf[it], vf[jv], o[it][jv], 0, 0, 0);
    }

    // prefetch proj B-frags jt=0,1 + all 8 proj biases (issued before the barriers,
    // cannot be sunk past them -> latency overlaps O round-trip)
    short8 pcur[4], pnxt[4];
    float pbv[8];
    #pragma unroll
    for (int ks = 0; ks < 4; ++ks) {
        pcur[ks] = *(const short8a*)(wproj + cc * DIM + ks * 32 + qq * 8);
        pnxt[ks] = *(const short8a*)(wproj + (16 + cc) * DIM + ks * 32 + qq * 8);
    }
    #pragma unroll
    for (int j = 0; j < 8; ++j) pbv[j] = projb[j * 16 + cc];

    __syncthreads();   // B3: all PV reads done -> O may overlay waves 0-1 regions

    short* ow = (short*)pool;   // O [64 tokens][OSTR=136], features 0..127
    #pragma unroll
    for (int it = 0; it < 4; ++it)
        #pragma unroll
        for (int jv = 0; jv < 2; ++jv)
            #pragma unroll
            for (int r = 0; r < 4; ++r) {
                int t = it * 16 + qq * 4 + r;
                ow[t * OSTR + wave * 32 + jv * 16 + cc] = f2b(o[it][jv][r]);
            }
    __syncthreads();   // B4: O visible

    // ---------------- Phase 4: proj GEMM (depth-2 pipelined B-frags) ----------------
    {
        short8 a2[4];
        #pragma unroll
        for (int ks = 0; ks < 4; ++ks)
            a2[ks] = *(const short8a*)(ow + (wave * 16 + cc) * OSTR + ks * 32 + qq * 8);
        float* outb = out + (size_t)b * NT * DIM;
        #pragma unroll
        for (int jt = 0; jt < 8; ++jt) {
            short8 pfut[4];
            if (jt < 6) {
                int cn = (jt + 2) * 16 + cc;
                #pragma unroll
                for (int ks = 0; ks < 4; ++ks)
                    pfut[ks] = *(const short8a*)(wproj + cn * DIM + ks * 32 + qq * 8);
            }
            float pb = pbv[jt];
            floatx4 acc = {pb, pb, pb, pb};
            #pragma unroll
            for (int ks = 0; ks < 4; ++ks)
                acc = __builtin_amdgcn_mfma_f32_16x16x32_bf16(a2[ks], pcur[ks], acc, 0, 0, 0);
            int col = jt * 16 + cc;
            #pragma unroll
            for (int r = 0; r < 4; ++r) {
                int row = wave * 16 + qq * 4 + r;
                if (row < NT) outb[row * DIM + col] = acc[r];
            }
            #pragma unroll
            for (int ks = 0; ks < 4; ++ks) { pcur[ks] = pnxt[ks]; pnxt[ks] = pfut[ks]; }
        }
    }
}

extern "C" void kernel_launch(void* const* d_in, const int* in_sizes, int n_in,
                              void* d_out, int out_size, void* d_ws, size_t ws_size,
                              hipStream_t stream) {
    const float* x     = (const float*)d_in[0];   // (4096,49,128)
    const float* mask  = (const float*)d_in[1];   // (64,49,49)
    const float* qkvw  = (const float*)d_in[2];   // (384,128)
    const float* qkvb  = (const float*)d_in[3];   // (384)
    const float* projw = (const float*)d_in[4];   // (128,128)
    const float* projb = (const float*)d_in[5];   // (128)
    const float* btab  = (const float*)d_in[6];   // (169,4)
    const int*   ridx  = (const int*)d_in[7];     // (49,49)
    float* outp = (float*)d_out;

    short* wqkv  = (short*)d_ws;                      //   98304 B
    short* wproj = (short*)((char*)d_ws + 98304);     //   32768 B
    short* cmb   = (short*)((char*)d_ws + 131072);    // 2097152 B (total 2.23 MB)

    wmsa_prep<<<4096, 256, 0, stream>>>(qkvw, projw, btab, ridx, mask, wqkv, wproj, cmb);
    wmsa_main<<<4096, 256, 0, stream>>>(x, qkvb, projb, wqkv, wproj, cmb, outp);
}